// Round 11
// baseline (129.469 us; speedup 1.0000x reference)
//
#include <hip/hip_runtime.h>
#include <hip/hip_bf16.h>
#include <stdint.h>
#include <math.h>

// MMD: N=8192 rows (4096 source + 4096 target), D=256, fp32 in, scalar fp32 out.
// result = (1/4096^2) * sum_ij s_i s_j ksum(L2_ij),  s_i = +1 (i<4096) else -1
// ksum = w + w^2 + w^4 + w^8 + w^16,  w = exp(-L2/(16 bw0))
// bw0 = [2N*sum(sq) - 2*sum_d colsum_d^2] / (N^2-N) / 4  (analytic sum(L2))
// R1: same-address fp64 CAS atomics catastrophic. R2: XOR swizzle for LDS.
// R5 FAILED: agent fences. R6 (98us) fp8 splitK. R7 FAILED: pair-tile,
//     8 waves/CU. R8 (94.5us). R9/R10 FAILED: intra-tile overlap.
// R11: 512-blk kconv +5.4us. R12 (93.88 BEST): MXFP4 whole-K 128-tile.
// R13 FAILED: cooperative. R14/R15/R16: atomic finishes dead (fences or
//     counter serialization). R17 (108): persistent null; kgemm 42-43us,
//     VALU 19%, Mfma 3.4%, Occ 29% -> latency-bound, concurrency ~1-2.
// R18 (93.887): 8-wave lean-acc variant IDENTICAL to R12 -> kgemm invariant
//     to schedule/bytes/occupancy-tweaks at 128-tile granularity. 2080 tiny
//     latency chains x 8.1 rounds is the structure itself.
// R19: 256x256 tiles. 528 blocks (496 off-diag + 32 diag), 1024 thr =
//     16 waves, 64KB LDS whole-K A+B -> 2 blk/CU = 32 waves/CU potential.
//     Tile processed in 4 col-strips of 64 (acc = 16 regs/wave; epilogue
//     fused per strip). 4x MFMA per block, 4x fewer chains, rounds 8.1->2.
//     launch_bounds(1024,8) targets <=64 VGPR.

#define NTOT 8192
#define DDIM 256
#define BT 256        // tile side
#define RB 128        // row bytes (256 fp4)
#define NBLK 528      // 32*33/2 tiles incl. diagonal
#define NTILE 32      // 8192/256

typedef int i32x8 __attribute__((ext_vector_type(8)));
typedef int i32x4 __attribute__((ext_vector_type(4)));
typedef float f32x4 __attribute__((ext_vector_type(4)));

__device__ __forceinline__ void gl_lds16(const void* g, void* l) {
  __builtin_amdgcn_global_load_lds(
      (const __attribute__((address_space(1))) void*)g,
      (__attribute__((address_space(3))) void*)l, 16, 0, 0);
}

// fp32 -> e2m1 quantize: returns dequant value v and 4-bit code c.
// Self-consistent: v is EXACTLY what the MFMA dequantizes code c to.
__device__ __forceinline__ void q4(float x, float& v, int& c) {
  float a = fabsf(x);
  float av; int m;
  if (a < 0.25f)      { av = 0.0f; m = 0; }
  else if (a < 0.75f) { av = 0.5f; m = 1; }
  else if (a < 1.25f) { av = 1.0f; m = 2; }
  else if (a < 1.75f) { av = 1.5f; m = 3; }
  else if (a < 2.5f)  { av = 2.0f; m = 4; }
  else if (a < 3.5f)  { av = 3.0f; m = 5; }
  else if (a < 5.0f)  { av = 4.0f; m = 6; }
  else                { av = 6.0f; m = 7; }
  v = copysignf(av, x);
  c = ((__float_as_uint(x) >> 31) << 3) | m;
}

// ---- fp32 -> fp4(e2m1) convert + per-row sq + f32-atomic column/sq sums ----
// 256 blocks x 1024 threads (R15-vs-R16 measured ~3.5us better than 256-thr).
__global__ __launch_bounds__(1024) void kconv(const float* __restrict__ src,
                                              const float* __restrict__ tgt,
                                              unsigned char* __restrict__ X4,
                                              float* __restrict__ sq,
                                              float* __restrict__ colsum,  // [256]
                                              float* __restrict__ ssqacc) {
  int b = blockIdx.x;           // 256 blocks, 32 rows each
  int t = threadIdx.x;          // 0..1023
  int lane = t & 63, wave = t >> 6;   // 16 waves
  float cp0 = 0.f, cp1 = 0.f, cp2 = 0.f, cp3 = 0.f;
  float sqp = 0.f;

  #pragma unroll
  for (int it = 0; it < 2; ++it) {
    int row = b * 32 + it * 16 + wave;
    const float* base = (row < 4096) ? (src + (size_t)row * DDIM)
                                     : (tgt + (size_t)(row - 4096) * DDIM);
    float4 v = ((const float4*)base)[lane];
    float f0, f1, f2, f3; int c0, c1, c2, c3;
    q4(v.x, f0, c0); q4(v.y, f1, c1); q4(v.z, f2, c2); q4(v.w, f3, c3);
    unsigned short pk = (unsigned short)(c0 | (c1 << 4) | (c2 << 8) | (c3 << 12));
    ((unsigned short*)(X4 + (size_t)row * RB))[lane] = pk;
    cp0 += f0; cp1 += f1; cp2 += f2; cp3 += f3;
    float s = f0 * f0 + f1 * f1 + f2 * f2 + f3 * f3;
    #pragma unroll
    for (int off = 32; off; off >>= 1) s += __shfl_down(s, off);
    if (lane == 0) { sq[row] = s; sqp += s; }
  }

  __shared__ float cred[16][256];   // 16 KB
  __shared__ float sred[16];
  ((float4*)&cred[wave][lane * 4])[0] = make_float4(cp0, cp1, cp2, cp3);
  if (lane == 0) sred[wave] = sqp;
  __syncthreads();
  if (t < 256) {
    float csum = 0.f;
    #pragma unroll
    for (int w = 0; w < 16; ++w) csum += cred[w][t];
    atomicAdd(&colsum[t], csum);
  }
  if (t == 0) {
    float s2 = 0.f;
    #pragma unroll
    for (int w = 0; w < 16; ++w) s2 += sred[w];
    atomicAdd(ssqacc, s2);
  }
}

// ---- main: 256x256 tiles, MX-fp4 whole-K, 16 waves, 2 blk/CU ----
// 4 col-strips of 64, fused epilogue per strip, acc = 16 regs/wave.
__global__ __launch_bounds__(1024, 8) void kgemm(const unsigned char* __restrict__ X4,
                                                 const float* __restrict__ sq,
                                                 const float* __restrict__ colsum,
                                                 const float* __restrict__ ssqacc,
                                                 double* __restrict__ Spart) {
  int b = blockIdx.x;
  // triangular (incl. diag): offset(tr) = 32*tr - tr*(tr-1)/2
  int tr = (int)((65.0 - sqrt(65.0 * 65.0 - 8.0 * (double)b)) * 0.5);
  while (tr > 0 && (32 * tr - tr * (tr - 1) / 2) > b) --tr;
  while ((32 * (tr + 1) - (tr + 1) * tr / 2) <= b) ++tr;
  int tc = tr + (b - (32 * tr - tr * (tr - 1) / 2));
  bool diag = (tr == tc);

  __shared__ alignas(16) unsigned char Ash[BT * RB];   // 32 KB (whole K, fp4)
  __shared__ alignas(16) unsigned char Bsh[BT * RB];   // 32 KB
  __shared__ float sqR2[BT], sqC2[BT];                 // 2 KB
  __shared__ double red[16];

  int t = threadIdx.x;            // 0..1023
  int wave = t >> 6, lane = t & 63;
  int mrow = lane & 15, q = lane >> 4;
  int sw = mrow & 7;
  int rg = wave >> 2;             // row group: rows [rg*64, rg*64+64)
  int cg = wave & 3;              // col group within strip: 16 cols
  const int sone = 0x7F7F7F7F;    // e8m0 scale = 1.0

  const unsigned char* Ag = X4 + (size_t)tr * BT * RB;
  const unsigned char* Bg = X4 + (size_t)tc * BT * RB;

  // ---- issue whole-K staging FIRST (bw0 compute hides behind it) ----
  // 2048 16B-chunks per matrix; 2 per thread; XOR swizzle within 8-chunk row.
  #pragma unroll
  for (int cc = 0; cc < 2; ++cc) {
    int c = t + cc * 1024;
    int row = c >> 3, kcs = c & 7;
    int kc = kcs ^ (row & 7);
    gl_lds16(Ag + (size_t)row * RB + kc * 16, Ash + c * 16);
  }
  if (!diag) {
    #pragma unroll
    for (int cc = 0; cc < 2; ++cc) {
      int c = t + cc * 1024;
      int row = c >> 3, kcs = c & 7;
      int kc = kcs ^ (row & 7);
      gl_lds16(Bg + (size_t)row * RB + kc * 16, Bsh + c * 16);
    }
  }

  // ---- wave-redundant bw0: colsum^2 sum + ssq, 6 shuffle rounds, no LDS ----
  float4 cv = ((const float4*)colsum)[lane];
  float scp = cv.x * cv.x + cv.y * cv.y + cv.z * cv.z + cv.w * cv.w;
  #pragma unroll
  for (int off = 32; off; off >>= 1) scp += __shfl_down(scp, off);
  scp = __shfl(scp, 0);                 // Σ colsum_d^2 (all lanes)
  float ssq = *ssqacc;
  double sumL2 = 2.0 * 8192.0 * (double)ssq - 2.0 * (double)scp;
  double bw0 = sumL2 / (8192.0 * 8192.0 - 8192.0) / 4.0;
  float kk = (float)(-1.44269504088896 / (16.0 * bw0));  // cs * log2(e)
  float a2s = -2.f * kk;

  if (t < 256)      sqR2[t] = kk * sq[tr * BT + t];
  else if (t < 512) sqC2[t - 256] = kk * sq[tc * BT + (t - 256)];

  __syncthreads();  // B1: staging + sqR2/sqC2 done (single drain per tile)

  const unsigned char* Bs = diag ? Ash : Bsh;
  float lsum = 0.f;
  int rq = q * 4, cl = mrow;

  // ---- 4 col-strips of 64; per strip: 8 MFMAs/wave + fused epilogue ----
  #pragma unroll
  for (int s = 0; s < 4; ++s) {
    f32x4 acc[4];
    #pragma unroll
    for (int i = 0; i < 4; ++i) acc[i] = (f32x4){0.f, 0.f, 0.f, 0.f};

    int colB = s * 64 + cg * 16 + mrow;   // B row = C col
    #pragma unroll
    for (int ks = 0; ks < 2; ++ks) {
      int kcsel = ((ks * 4 + q) ^ sw) * 16;
      i32x8 bf = (i32x8){0, 0, 0, 0, 0, 0, 0, 0};
      *(i32x4*)&bf = *(const i32x4*)&Bs[colB * RB + kcsel];
      #pragma unroll
      for (int rf = 0; rf < 4; ++rf) {
        i32x8 af = (i32x8){0, 0, 0, 0, 0, 0, 0, 0};
        *(i32x4*)&af = *(const i32x4*)&Ash[(rg * 64 + rf * 16 + mrow) * RB + kcsel];
        acc[rf] = __builtin_amdgcn_mfma_scale_f32_16x16x128_f8f6f4(
            af, bf, acc[rf], 4, 4, 0, sone, 0, sone);  // fmt 4 = fp4
      }
    }

    // fused epilogue for this strip
    // C/D layout col=lane&15, row=(lane>>4)*4+reg [m89/m91; dtype-indep]
    float sc = sqC2[s * 64 + cg * 16 + cl];
    #pragma unroll
    for (int rf = 0; rf < 4; ++rf) {
      int rbase = rg * 64 + rf * 16 + rq;
      #pragma unroll
      for (int j = 0; j < 4; ++j) {
        float x = fmaf(a2s, acc[rf][j], sqR2[rbase + j] + sc);
        float w = __builtin_amdgcn_exp2f(x);
        float w2 = w * w, w4 = w2 * w2, w8 = w4 * w4;
        lsum += ((w + w2) + (w4 + w8)) + w8 * w8;   // w+w2+w4+w8+w16
      }
    }
  }

  double wt = diag ? 1.0 : 2.0;
  if ((tr < 16) != (tc < 16)) wt = -wt;  // s_i*s_j uniform per 256-tile
  double ds = (double)lsum * wt;
  #pragma unroll
  for (int off = 32; off; off >>= 1) ds += __shfl_down(ds, off);
  if (lane == 0) red[wave] = ds;
  __syncthreads();  // B2
  if (t == 0) {
    double s = 0.0;
    #pragma unroll
    for (int w = 0; w < 16; ++w) s += red[w];
    Spart[b] = s;
  }
}

// ---- final reduce of 528 per-block partials ----
__global__ __launch_bounds__(256) void kfin(const double* __restrict__ Spart,
                                            float* __restrict__ out) {
  int t = threadIdx.x;
  double s = Spart[t] + ((t + 256 < NBLK) ? Spart[t + 256] : 0.0);
  if (t + 512 < NBLK) s += Spart[t + 512];
  __shared__ double red[256];
  red[t] = s;
  __syncthreads();
  for (int off = 128; off; off >>= 1) {
    if (t < off) red[t] += red[t + off];
    __syncthreads();
  }
  if (t == 0) out[0] = (float)(red[0] / (4096.0 * 4096.0));
}

extern "C" void kernel_launch(void* const* d_in, const int* in_sizes, int n_in,
                              void* d_out, int out_size, void* d_ws, size_t ws_size,
                              hipStream_t stream) {
  const float* src = (const float*)d_in[0];
  const float* tgt = (const float*)d_in[1];
  char* ws = (char*)d_ws;
  unsigned char* X4 = (unsigned char*)ws;             // 8192*128 = 1 MiB (fp4)
  float* sq      = (float*)(ws + 1048576);            // 32 KiB
  float* colsum  = (float*)(ws + 1081344);            // 256 f + 1 f (ssq)
  float* ssqacc  = colsum + 256;
  double* Spart  = (double*)(ws + 1083392);           // 528*8 = 4224 B
  float* out = (float*)d_out;

  hipMemsetAsync((void*)colsum, 0, 1040, stream);     // zero atomic targets
  hipLaunchKernelGGL(kconv, dim3(256), dim3(1024), 0, stream,
                     src, tgt, X4, sq, colsum, ssqacc);
  hipLaunchKernelGGL(kgemm, dim3(NBLK), dim3(1024), 0, stream,
                     X4, sq, colsum, ssqacc, Spart);
  hipLaunchKernelGGL(kfin, dim3(1), dim3(256), 0, stream, Spart, out);
}

// Round 13
// 98.631 us; speedup vs baseline: 1.3127x; 1.3127x over previous
//
#include <hip/hip_runtime.h>
#include <hip/hip_bf16.h>
#include <stdint.h>
#include <math.h>

// MMD: N=8192 rows (4096 source + 4096 target), D=256, fp32 in, scalar fp32 out.
// result = (1/4096^2) * sum_ij s_i s_j ksum(L2_ij),  s_i = +1 (i<4096) else -1
// ksum = w + w^2 + w^4 + w^8 + w^16,  w = exp(-L2/(16 bw0))
// bw0 = [2N*sum(sq) - 2*sum_d colsum_d^2] / (N^2-N) / 4  (analytic sum(L2))
// R1: same-address fp64 CAS atomics catastrophic. R2: XOR swizzle for LDS.
// R5 FAILED: agent fences. R6 (98us) fp8 splitK. R7 FAILED: pair-tile.
// R8 (94.5us). R9/R10 FAILED: intra-tile overlap. R11: 512-blk kconv +5.4us.
// R12 (93.88): MXFP4 whole-K 128-tile. R13 FAILED: cooperative.
// R14/R15/R16: atomic finishes dead. R17 (108): persistent null; kgemm
//     42us latency-bound (Occ 29%, VALU 19%, Mfma 3.4%).
// R18 (93.887): 8-wave lean-acc identical -> 128-tile structure invariant.
// R19 FAILED (129us) BUT MECHANISM CONFIRMED: 256-tile got Occupancy 54.6%
//     (vs 29%); launch_bounds(1024,8) forced 64-reg budget -> 32 VGPR + spill
//     (WRITE_SIZE 84.5MB scratch!) -> 60us. Spill ate the win.
// R20: R19 with budget fixed: launch_bounds(1024,4) (128-reg budget, ~55
//     needed -> no spill); col-strip loop unroll 1 (one strip live at a
//     time). LDS 68KB caps at 2 blk/CU = 32 waves/CU potential.
// R21: identical resubmit of R20 — round 12 was an infrastructure failure
//     (container died twice; no compile/correctness signal).

#define NTOT 8192
#define DDIM 256
#define BT 256        // tile side
#define RB 128        // row bytes (256 fp4)
#define NBLK 528      // 32*33/2 tiles incl. diagonal
#define NTILE 32      // 8192/256

typedef int i32x8 __attribute__((ext_vector_type(8)));
typedef int i32x4 __attribute__((ext_vector_type(4)));
typedef float f32x4 __attribute__((ext_vector_type(4)));

__device__ __forceinline__ void gl_lds16(const void* g, void* l) {
  __builtin_amdgcn_global_load_lds(
      (const __attribute__((address_space(1))) void*)g,
      (__attribute__((address_space(3))) void*)l, 16, 0, 0);
}

// fp32 -> e2m1 quantize: returns dequant value v and 4-bit code c.
// Self-consistent: v is EXACTLY what the MFMA dequantizes code c to.
__device__ __forceinline__ void q4(float x, float& v, int& c) {
  float a = fabsf(x);
  float av; int m;
  if (a < 0.25f)      { av = 0.0f; m = 0; }
  else if (a < 0.75f) { av = 0.5f; m = 1; }
  else if (a < 1.25f) { av = 1.0f; m = 2; }
  else if (a < 1.75f) { av = 1.5f; m = 3; }
  else if (a < 2.5f)  { av = 2.0f; m = 4; }
  else if (a < 3.5f)  { av = 3.0f; m = 5; }
  else if (a < 5.0f)  { av = 4.0f; m = 6; }
  else                { av = 6.0f; m = 7; }
  v = copysignf(av, x);
  c = ((__float_as_uint(x) >> 31) << 3) | m;
}

// ---- fp32 -> fp4(e2m1) convert + per-row sq + f32-atomic column/sq sums ----
// 256 blocks x 1024 threads (R15-vs-R16 measured ~3.5us better than 256-thr).
__global__ __launch_bounds__(1024) void kconv(const float* __restrict__ src,
                                              const float* __restrict__ tgt,
                                              unsigned char* __restrict__ X4,
                                              float* __restrict__ sq,
                                              float* __restrict__ colsum,  // [256]
                                              float* __restrict__ ssqacc) {
  int b = blockIdx.x;           // 256 blocks, 32 rows each
  int t = threadIdx.x;          // 0..1023
  int lane = t & 63, wave = t >> 6;   // 16 waves
  float cp0 = 0.f, cp1 = 0.f, cp2 = 0.f, cp3 = 0.f;
  float sqp = 0.f;

  #pragma unroll
  for (int it = 0; it < 2; ++it) {
    int row = b * 32 + it * 16 + wave;
    const float* base = (row < 4096) ? (src + (size_t)row * DDIM)
                                     : (tgt + (size_t)(row - 4096) * DDIM);
    float4 v = ((const float4*)base)[lane];
    float f0, f1, f2, f3; int c0, c1, c2, c3;
    q4(v.x, f0, c0); q4(v.y, f1, c1); q4(v.z, f2, c2); q4(v.w, f3, c3);
    unsigned short pk = (unsigned short)(c0 | (c1 << 4) | (c2 << 8) | (c3 << 12));
    ((unsigned short*)(X4 + (size_t)row * RB))[lane] = pk;
    cp0 += f0; cp1 += f1; cp2 += f2; cp3 += f3;
    float s = f0 * f0 + f1 * f1 + f2 * f2 + f3 * f3;
    #pragma unroll
    for (int off = 32; off; off >>= 1) s += __shfl_down(s, off);
    if (lane == 0) { sq[row] = s; sqp += s; }
  }

  __shared__ float cred[16][256];   // 16 KB
  __shared__ float sred[16];
  ((float4*)&cred[wave][lane * 4])[0] = make_float4(cp0, cp1, cp2, cp3);
  if (lane == 0) sred[wave] = sqp;
  __syncthreads();
  if (t < 256) {
    float csum = 0.f;
    #pragma unroll
    for (int w = 0; w < 16; ++w) csum += cred[w][t];
    atomicAdd(&colsum[t], csum);
  }
  if (t == 0) {
    float s2 = 0.f;
    #pragma unroll
    for (int w = 0; w < 16; ++w) s2 += sred[w];
    atomicAdd(ssqacc, s2);
  }
}

// ---- main: 256x256 tiles, MX-fp4 whole-K, 16 waves, target 2 blk/CU ----
// 4 col-strips of 64 processed SEQUENTIALLY (unroll 1 -> one strip live);
// acc = 16 regs/wave; fused epilogue per strip.
__global__ __launch_bounds__(1024, 4) void kgemm(const unsigned char* __restrict__ X4,
                                                 const float* __restrict__ sq,
                                                 const float* __restrict__ colsum,
                                                 const float* __restrict__ ssqacc,
                                                 double* __restrict__ Spart) {
  int b = blockIdx.x;
  // triangular (incl. diag): offset(tr) = 32*tr - tr*(tr-1)/2
  int tr = (int)((65.0 - sqrt(65.0 * 65.0 - 8.0 * (double)b)) * 0.5);
  while (tr > 0 && (32 * tr - tr * (tr - 1) / 2) > b) --tr;
  while ((32 * (tr + 1) - (tr + 1) * tr / 2) <= b) ++tr;
  int tc = tr + (b - (32 * tr - tr * (tr - 1) / 2));
  bool diag = (tr == tc);

  __shared__ alignas(16) unsigned char Ash[BT * RB];   // 32 KB (whole K, fp4)
  __shared__ alignas(16) unsigned char Bsh[BT * RB];   // 32 KB
  __shared__ float sqR2[BT], sqC2[BT];                 // 2 KB
  __shared__ double red[16];

  int t = threadIdx.x;            // 0..1023
  int wave = t >> 6, lane = t & 63;
  int mrow = lane & 15, q = lane >> 4;
  int sw = mrow & 7;
  int rg = wave >> 2;             // row group: rows [rg*64, rg*64+64)
  int cg = wave & 3;              // col group within strip: 16 cols
  const int sone = 0x7F7F7F7F;    // e8m0 scale = 1.0

  const unsigned char* Ag = X4 + (size_t)tr * BT * RB;
  const unsigned char* Bg = X4 + (size_t)tc * BT * RB;

  // ---- issue whole-K staging FIRST (bw0 compute hides behind it) ----
  // 2048 16B-chunks per matrix; 2 per thread; XOR swizzle within 8-chunk row.
  #pragma unroll
  for (int cc = 0; cc < 2; ++cc) {
    int c = t + cc * 1024;
    int row = c >> 3, kcs = c & 7;
    int kc = kcs ^ (row & 7);
    gl_lds16(Ag + (size_t)row * RB + kc * 16, Ash + c * 16);
  }
  if (!diag) {
    #pragma unroll
    for (int cc = 0; cc < 2; ++cc) {
      int c = t + cc * 1024;
      int row = c >> 3, kcs = c & 7;
      int kc = kcs ^ (row & 7);
      gl_lds16(Bg + (size_t)row * RB + kc * 16, Bsh + c * 16);
    }
  }

  // ---- wave-redundant bw0: colsum^2 sum + ssq, 6 shuffle rounds, no LDS ----
  float4 cv = ((const float4*)colsum)[lane];
  float scp = cv.x * cv.x + cv.y * cv.y + cv.z * cv.z + cv.w * cv.w;
  #pragma unroll
  for (int off = 32; off; off >>= 1) scp += __shfl_down(scp, off);
  scp = __shfl(scp, 0);                 // Σ colsum_d^2 (all lanes)
  float ssq = *ssqacc;
  double sumL2 = 2.0 * 8192.0 * (double)ssq - 2.0 * (double)scp;
  double bw0 = sumL2 / (8192.0 * 8192.0 - 8192.0) / 4.0;
  float kk = (float)(-1.44269504088896 / (16.0 * bw0));  // cs * log2(e)
  float a2s = -2.f * kk;

  if (t < 256)      sqR2[t] = kk * sq[tr * BT + t];
  else if (t < 512) sqC2[t - 256] = kk * sq[tc * BT + (t - 256)];

  __syncthreads();  // B1: staging + sqR2/sqC2 done (single drain per tile)

  const unsigned char* Bs = diag ? Ash : Bsh;
  float lsum = 0.f;
  int rq = q * 4, cl = mrow;

  // ---- 4 col-strips of 64; per strip: 8 MFMAs/wave + fused epilogue ----
  #pragma unroll 1
  for (int s = 0; s < 4; ++s) {
    f32x4 acc[4];
    #pragma unroll
    for (int i = 0; i < 4; ++i) acc[i] = (f32x4){0.f, 0.f, 0.f, 0.f};

    int colB = s * 64 + cg * 16 + mrow;   // B row = C col
    #pragma unroll
    for (int ks = 0; ks < 2; ++ks) {
      int kcsel = ((ks * 4 + q) ^ sw) * 16;
      i32x8 bf = (i32x8){0, 0, 0, 0, 0, 0, 0, 0};
      *(i32x4*)&bf = *(const i32x4*)&Bs[colB * RB + kcsel];
      #pragma unroll
      for (int rf = 0; rf < 4; ++rf) {
        i32x8 af = (i32x8){0, 0, 0, 0, 0, 0, 0, 0};
        *(i32x4*)&af = *(const i32x4*)&Ash[(rg * 64 + rf * 16 + mrow) * RB + kcsel];
        acc[rf] = __builtin_amdgcn_mfma_scale_f32_16x16x128_f8f6f4(
            af, bf, acc[rf], 4, 4, 0, sone, 0, sone);  // fmt 4 = fp4
      }
    }

    // fused epilogue for this strip
    // C/D layout col=lane&15, row=(lane>>4)*4+reg [m89/m91; dtype-indep]
    float sc = sqC2[s * 64 + cg * 16 + cl];
    #pragma unroll
    for (int rf = 0; rf < 4; ++rf) {
      int rbase = rg * 64 + rf * 16 + rq;
      #pragma unroll
      for (int j = 0; j < 4; ++j) {
        float x = fmaf(a2s, acc[rf][j], sqR2[rbase + j] + sc);
        float w = __builtin_amdgcn_exp2f(x);
        float w2 = w * w, w4 = w2 * w2, w8 = w4 * w4;
        lsum += ((w + w2) + (w4 + w8)) + w8 * w8;   // w+w2+w4+w8+w16
      }
    }
  }

  double wt = diag ? 1.0 : 2.0;
  if ((tr < 16) != (tc < 16)) wt = -wt;  // s_i*s_j uniform per 256-tile
  double ds = (double)lsum * wt;
  #pragma unroll
  for (int off = 32; off; off >>= 1) ds += __shfl_down(ds, off);
  if (lane == 0) red[wave] = ds;
  __syncthreads();  // B2
  if (t == 0) {
    double s = 0.0;
    #pragma unroll
    for (int w = 0; w < 16; ++w) s += red[w];
    Spart[b] = s;
  }
}

// ---- final reduce of 528 per-block partials ----
__global__ __launch_bounds__(256) void kfin(const double* __restrict__ Spart,
                                            float* __restrict__ out) {
  int t = threadIdx.x;
  double s = Spart[t] + ((t + 256 < NBLK) ? Spart[t + 256] : 0.0);
  if (t + 512 < NBLK) s += Spart[t + 512];
  __shared__ double red[256];
  red[t] = s;
  __syncthreads();
  for (int off = 128; off; off >>= 1) {
    if (t < off) red[t] += red[t + off];
    __syncthreads();
  }
  if (t == 0) out[0] = (float)(red[0] / (4096.0 * 4096.0));
}

extern "C" void kernel_launch(void* const* d_in, const int* in_sizes, int n_in,
                              void* d_out, int out_size, void* d_ws, size_t ws_size,
                              hipStream_t stream) {
  const float* src = (const float*)d_in[0];
  const float* tgt = (const float*)d_in[1];
  char* ws = (char*)d_ws;
  unsigned char* X4 = (unsigned char*)ws;             // 8192*128 = 1 MiB (fp4)
  float* sq      = (float*)(ws + 1048576);            // 32 KiB
  float* colsum  = (float*)(ws + 1081344);            // 256 f + 1 f (ssq)
  float* ssqacc  = colsum + 256;
  double* Spart  = (double*)(ws + 1083392);           // 528*8 = 4224 B
  float* out = (float*)d_out;

  hipMemsetAsync((void*)colsum, 0, 1040, stream);     // zero atomic targets
  hipLaunchKernelGGL(kconv, dim3(256), dim3(1024), 0, stream,
                     src, tgt, X4, sq, colsum, ssqacc);
  hipLaunchKernelGGL(kgemm, dim3(NBLK), dim3(1024), 0, stream,
                     X4, sq, colsum, ssqacc, Spart);
  hipLaunchKernelGGL(kfin, dim3(1), dim3(256), 0, stream, Spart, out);
}